// Round 5
// baseline (144.353 us; speedup 1.0000x reference)
//
#include <hip/hip_runtime.h>
#include <hip/hip_bf16.h>

// Problem constants
#define BATCH 4
#define DIM 512
#define HEADS 8
#define CH 64          // DIM/HEADS
#define SEQ 2048
#define C3 1536        // 3*DIM
#define L2EPS 1e-12f

typedef float f32x4 __attribute__((ext_vector_type(4)));
typedef short s16x8 __attribute__((ext_vector_type(8)));
typedef unsigned short ushort_t;

// f32 pair -> packed bf16 pair (RNE) — bit version (memory-bound kernels)
static __device__ __forceinline__ unsigned bfpair(float a, float b) {
  unsigned ua = __builtin_bit_cast(unsigned, a);
  unsigned ub = __builtin_bit_cast(unsigned, b);
  ua = (ua + 0x7FFFu + ((ua >> 16) & 1u)) >> 16;
  ub = (ub + 0x7FFFu + ((ub >> 16) & 1u)) >> 16;
  return ua | (ub << 16);
}

// f32 pair -> packed bf16 pair via HW cvt (VALU-critical kernels)
static __device__ __forceinline__ unsigned cvtpk(float lo, float hi) {
  unsigned r;
  asm("v_cvt_pk_bf16_f32 %0, %1, %2" : "=v"(r) : "v"(lo), "v"(hi));
  return r;
}

// single-instruction exp2 (skip OCML's denormal-guard expansion; |x|<=~92 here)
static __device__ __forceinline__ float fexp2(float x) {
  float r;
  asm("v_exp_f32 %0, %1" : "=v"(r) : "v"(x));
  return r;
}

// async global->LDS, 16B per lane; lds dest must be wave-uniform base
static __device__ __forceinline__ void gl_lds16(const void* g, void* l) {
  __builtin_amdgcn_global_load_lds(
      (const __attribute__((address_space(1))) unsigned int*)g,
      (__attribute__((address_space(3))) unsigned int*)l, 16, 0, 0);
}

// ---------------------------------------------------------------------------
// Weight prep: f32 [M][512] -> bf16 [M][512], XOR-swizzled per 64-k chunk.
// (swizzle needed: GEMM stages via global_load_lds)
// ---------------------------------------------------------------------------
__global__ __launch_bounds__(256) void wprep(
    const float* __restrict__ wq, const float* __restrict__ wp,
    unsigned* __restrict__ wqb, unsigned* __restrict__ wpb) {
  const int id = blockIdx.x * 256 + threadIdx.x;
  const float* src;
  unsigned* dst;
  int rid;
  if (id < 1536 * 256) { src = wq; dst = wqb; rid = id; }
  else                 { src = wp; dst = wpb; rid = id - 1536 * 256; }
  const int m = rid >> 8, dcol = rid & 255;
  const int chunk = dcol >> 5, dw = dcol & 31;
  const int sdw = chunk * 32 + (dw ^ (4 * (m & 7)));
  const float* s = src + (size_t)m * 512 + 2 * sdw;
  dst[rid] = bfpair(s[0], s[1]);
}

// ---------------------------------------------------------------------------
// x transpose: f32 x[b][k][n] -> bf16 xbt[b][n][k], swizzled per 64-k chunk.
// ---------------------------------------------------------------------------
__global__ __launch_bounds__(256) void xpose_bf16(
    const float* __restrict__ x, unsigned* __restrict__ xbt) {
  __shared__ unsigned T[64][32];
  const int b = blockIdx.z;
  const int k0 = blockIdx.y * 64;
  const int n0 = blockIdx.x * 64;
  const int nl = threadIdx.x & 63;
  const int dwg = threadIdx.x >> 6;
  const float* xb = x + ((size_t)b * DIM + k0) * SEQ + n0 + nl;
#pragma unroll
  for (int dd = 0; dd < 8; ++dd) {
    const int dw = dwg * 8 + dd;
    const float v0 = xb[(size_t)(2 * dw) * SEQ];
    const float v1 = xb[(size_t)(2 * dw + 1) * SEQ];
    T[nl][dw ^ (4 * (nl & 7))] = bfpair(v0, v1);
  }
  __syncthreads();
#pragma unroll
  for (int rep = 0; rep < 8; ++rep) {
    const int id = rep * 256 + threadIdx.x;
    const int row = id >> 5, dw = id & 31;
    xbt[((size_t)b * SEQ + n0 + row) * 256 + (k0 >> 1) + dw] = T[row][dw];
  }
}

// ---------------------------------------------------------------------------
// bf16 MFMA GEMM: Y[b][m][n] = sum_k W[m][k] * B[b][n][k] + bias[m], K=512.
// ---------------------------------------------------------------------------
__global__ __launch_bounds__(256) void gemm_mfma_bf16(
    const ushort_t* __restrict__ Wb, const ushort_t* __restrict__ Bt,
    const float* __restrict__ bias, float* __restrict__ Y,
    int M, int N) {
  __shared__ __align__(16) char lds[32768];
  char* As = lds;
  char* Bs = lds + 16384;
  const int b = blockIdx.z;
  const int m0 = blockIdx.y * 128, n0 = blockIdx.x * 128;
  const int t = threadIdx.x, w = t >> 6, lane = t & 63;
  const int l15 = lane & 15, g = lane >> 4;
  const int key = 16 * (l15 & 7);
  const int wm = (w >> 1) * 64, wn = (w & 1) * 64;

  const int rsub = lane >> 3;
  const int csub = (lane & 7) * 8;

  f32x4 acc[4][4] = {};

  const ushort_t* Ag0 = Wb + (size_t)(m0 + 32 * w + rsub) * 512 + csub;
  const ushort_t* Bg0 = Bt + ((size_t)b * N + n0 + 32 * w + rsub) * 512 + csub;
  char* Al0 = As + (32 * w) * 128;
  char* Bl0 = Bs + (32 * w) * 128;

  for (int kc = 0; kc < 8; ++kc) {
    const int ko64 = kc * 64;
#pragma unroll
    for (int ri = 0; ri < 4; ++ri) {
      gl_lds16(Ag0 + (size_t)(8 * ri) * 512 + ko64, Al0 + ri * 1024);
      gl_lds16(Bg0 + (size_t)(8 * ri) * 512 + ko64, Bl0 + ri * 1024);
    }
    __syncthreads();
    const char* Abase = As + (wm + l15) * 128;
    const char* Bbase = Bs + (wn + l15) * 128;
#pragma unroll
    for (int ks = 0; ks < 2; ++ks) {
      const int ko = (64 * ks + 16 * g) ^ key;
      s16x8 af[4], bf[4];
#pragma unroll
      for (int mf = 0; mf < 4; ++mf) af[mf] = *(const s16x8*)(Abase + mf * 2048 + ko);
#pragma unroll
      for (int nf = 0; nf < 4; ++nf) bf[nf] = *(const s16x8*)(Bbase + nf * 2048 + ko);
#pragma unroll
      for (int mf = 0; mf < 4; ++mf)
#pragma unroll
        for (int nf = 0; nf < 4; ++nf)
          acc[mf][nf] = __builtin_amdgcn_mfma_f32_16x16x32_bf16(
              af[mf], bf[nf], acc[mf][nf], 0, 0, 0);
    }
    __syncthreads();
  }

#pragma unroll
  for (int mf = 0; mf < 4; ++mf) {
#pragma unroll
    for (int rg = 0; rg < 4; ++rg) {
      const int m = m0 + wm + 16 * mf + 4 * g + rg;
      const float bv = bias[m];
      float* yp = Y + ((size_t)b * M + m) * N + n0 + wn + l15;
#pragma unroll
      for (int nf = 0; nf < 4; ++nf)
        yp[16 * nf] = acc[mf][nf][rg] + bv;
    }
  }
}

// ---------------------------------------------------------------------------
// Depthwise conv k=3 pad=1 + bias. One block per (b,channel) row, 8 n/thread.
// q channels -> f32 qkv + fused qnorm; k -> f32 qkv
// v channels -> bf16 vb[bh][jt128][cc][128 j] (plain row-major, natural j)
// ---------------------------------------------------------------------------
__global__ __launch_bounds__(256) void dwconv2(
    const float* __restrict__ pre, const float* __restrict__ wdw,
    const float* __restrict__ bdw, float* __restrict__ qkv,
    unsigned* __restrict__ vb, float* __restrict__ rq) {
  __shared__ float red[4];
  const int row = blockIdx.x;           // b*1536 + o
  const int o = row % C3;
  const int b = row / C3;
  const int n0 = threadIdx.x * 8;
  const float* src = pre + (size_t)row * SEQ + n0;
  float4 m0 = *(const float4*)src;
  float4 m1 = *(const float4*)(src + 4);
  const float left  = (n0 > 0) ? src[-1] : 0.f;
  const float right = (n0 < SEQ - 8) ? src[8] : 0.f;
  const float w0 = wdw[o * 3 + 0], w1 = wdw[o * 3 + 1], w2 = wdw[o * 3 + 2];
  const float bv = bdw[o];
  const float mid[8] = {m0.x, m0.y, m0.z, m0.w, m1.x, m1.y, m1.z, m1.w};
  const float lf[8]  = {left, m0.x, m0.y, m0.z, m0.w, m1.x, m1.y, m1.z};
  const float rt[8]  = {m0.y, m0.z, m0.w, m1.x, m1.y, m1.z, m1.w, right};
  float y[8];
#pragma unroll
  for (int u = 0; u < 8; ++u) y[u] = w0 * lf[u] + w1 * mid[u] + w2 * rt[u] + bv;

  if (o < 2 * DIM) {
    float* dst = qkv + (size_t)row * SEQ + n0;
    *(float4*)dst = make_float4(y[0], y[1], y[2], y[3]);
    *(float4*)(dst + 4) = make_float4(y[4], y[5], y[6], y[7]);
    if (o < DIM) {  // uniform branch: whole block is one q row
      float s = 0.f;
#pragma unroll
      for (int u = 0; u < 8; ++u) s += y[u] * y[u];
#pragma unroll
      for (int off = 32; off > 0; off >>= 1) s += __shfl_down(s, off);
      if ((threadIdx.x & 63) == 0) red[threadIdx.x >> 6] = s;
      __syncthreads();
      if (threadIdx.x == 0) {
        const float tv = red[0] + red[1] + red[2] + red[3];
        rq[b * DIM + o] = 1.0f / fmaxf(sqrtf(tv), L2EPS);
      }
    }
  } else {
    const int oc = o - 2 * DIM;
    const int h = oc >> 6, cc = oc & 63;
    const int bh = b * 8 + h;
    const int jt = n0 >> 7, jl = n0 & 127;
    uint4 pk;
    pk.x = bfpair(y[0], y[1]); pk.y = bfpair(y[2], y[3]);
    pk.z = bfpair(y[4], y[5]); pk.w = bfpair(y[6], y[7]);
    *(uint4*)&vb[((size_t)(bh * 16 + jt) * 64 + cc) * 64 + (jl >> 1)] = pk;
  }
}

// ---------------------------------------------------------------------------
// k norm over HEAD axis: rk[b][cc][n]
// ---------------------------------------------------------------------------
__global__ __launch_bounds__(256) void knorm_kernel(
    const float* __restrict__ qkv, float* __restrict__ rk) {
  const int idx = blockIdx.x * 256 + threadIdx.x;
  const int n = idx & (SEQ - 1);
  const int cc = (idx >> 11) & 63;
  const int b = idx >> 17;
  const float* base = qkv + ((size_t)b * C3 + DIM + cc) * SEQ + n;
  float s = 0.f;
#pragma unroll
  for (int h = 0; h < HEADS; ++h) {
    float v = base[(size_t)h * CH * SEQ];
    s += v * v;
  }
  rk[idx] = 1.0f / fmaxf(sqrtf(s), L2EPS);
}

// ---------------------------------------------------------------------------
// prep2: coalesced LDS-transpose build of qt / kt (both PLAIN c-order now;
// XOR swizzle only inside the LDS tile to kill write-bank conflicts).
//  sec0: qt rows PERMUTED within each 32-row slice: Q row jl stored at
//        position 16*((jl>>2)&1) + 4*(jl>>3) + (jl&3)  — makes QK^T C-layout
//        feed PV's K=32 B-operand directly (k = 8g+e == natural j for V).
//  sec1: kt plain, * rk * temp * log2(e)
// ---------------------------------------------------------------------------
__global__ __launch_bounds__(256) void prep2(
    const float* __restrict__ qkv, const float* __restrict__ rq,
    const float* __restrict__ rk, const float* __restrict__ temp,
    unsigned* __restrict__ qt, unsigned* __restrict__ kt) {
  __shared__ unsigned T[64][32];
  const int jt = blockIdx.x, bh = blockIdx.y, sec = blockIdx.z;
  const int b = bh >> 3, h = bh & 7;
  const int jl = threadIdx.x & 63, dwg = threadIdx.x >> 6;
  const int j = jt * 64 + jl;
  if (sec == 0) {
    const float* base = qkv + ((size_t)b * C3 + h * CH) * SEQ + j;
    const float* rqb = rq + b * DIM + h * CH;
#pragma unroll
    for (int dd = 0; dd < 8; ++dd) {
      const int dw = dwg * 8 + dd;
      float v0 = base[(size_t)(2 * dw) * SEQ] * rqb[2 * dw];
      float v1 = base[(size_t)(2 * dw + 1) * SEQ] * rqb[2 * dw + 1];
      T[jl][dw ^ (4 * (jl & 7))] = bfpair(v0, v1);
    }
  } else {
    const float f = temp[h] * 1.44269504f;
    const float* base = qkv + ((size_t)b * C3 + DIM + h * CH) * SEQ + j;
    const float* rkb = rk + (size_t)b * CH * SEQ + j;
#pragma unroll
    for (int dd = 0; dd < 8; ++dd) {
      const int dw = dwg * 8 + dd;
      float v0 = base[(size_t)(2 * dw) * SEQ] * rkb[(size_t)(2 * dw) * SEQ] * f;
      float v1 = base[(size_t)(2 * dw + 1) * SEQ] * rkb[(size_t)(2 * dw + 1) * SEQ] * f;
      T[jl][dw ^ (4 * (jl & 7))] = bfpair(v0, v1);
    }
  }
  __syncthreads();
  unsigned* dst = (sec == 0 ? qt : kt) + ((size_t)bh * SEQ + jt * 64) * 32;
#pragma unroll
  for (int rep = 0; rep < 8; ++rep) {
    const int id = rep * 256 + threadIdx.x;
    const int row = id >> 5, dw = id & 31;
    const unsigned val = T[row][dw ^ (4 * (row & 7))];
    int dstrow = row;
    if (sec == 0) {
      const int s = row >> 5, rl = row & 31;
      dstrow = (s << 5) | (16 * ((rl >> 2) & 1) + 4 * (rl >> 3) + (rl & 3));
    }
    dst[dstrow * 32 + dw] = val;
  }
}

// ---------------------------------------------------------------------------
// Flash attention v6: KVBLK=128, wave owns a 32-j slice, ALL MFMA 16x16x32.
//  QK^T: 2 row-groups x 4 ib x 2 K-halves = 16 MFMA.  The qt row permutation
//  makes pb (exp of st, packed e = 4*grp+rg) a valid K=32 B-operand with
//  k == natural j, so V is consumed in plain row-major order.
//  PV: 4 ib x 4 mf = 16 MFMA at full K=32 rate (was K=16 half-rate).
//  Register-resident, barrier-free; single-buffered frags with reloads
//  placed right after last use (~400cyc cover vs ~200cyc L2 latency).
// ---------------------------------------------------------------------------
__global__ __launch_bounds__(256, 2) void flash_mfma(
    const ushort_t* __restrict__ qt, const ushort_t* __restrict__ kt,
    const ushort_t* __restrict__ vb, unsigned* __restrict__ attn_t) {
  __shared__ __align__(16) char lds[17408];  // 16KB reduce scratch + 1KB l

  // XCD-aware bijective swizzle: each XCD handles 4 bh values (L2 locality)
  const int orig = blockIdx.y * 32 + blockIdx.x;
  const int swz = (orig & 7) * 128 + (orig >> 3);
  const int bh = swz >> 5, b = bh >> 3, h = bh & 7;
  const int i0 = (swz & 31) * 64;

  const int t = threadIdx.x, w = t >> 6, lane = t & 63;
  const int l15 = lane & 15, g = lane >> 4;

  // K fragments for all 4 i-blocks (wave-invariant): 32 VGPR
  const ushort_t* ktp = kt + ((size_t)bh * SEQ + i0 + l15) * 64 + 8 * g;
  s16x8 kf0[4], kf1[4];
#pragma unroll
  for (int ib = 0; ib < 4; ++ib) {
    kf0[ib] = *(const s16x8*)(ktp + ib * 1024);
    kf1[ib] = *(const s16x8*)(ktp + ib * 1024 + 32);
  }

  // Q: wave w's 32-position slice; grp adds 16 rows (=1024 ushorts);
  // jt128 adds 128 rows (=8192 ushorts). Per-lane row = l15, c-off = 8g.
  const ushort_t* qp = qt + ((size_t)bh * SEQ + 32 * w + l15) * 64 + 8 * g;
  // V: vb[bh][jt][cc][128]: lane row cc = 16mf + l15, j-off = 32w + 8g;
  // mf adds 16*128 ushorts, jt adds 64*128 = 8192 ushorts.
  const ushort_t* vp =
      vb + (((size_t)bh * 16) * 64 + l15) * 128 + 32 * w + 8 * g;

  f32x4 accO[4][4] = {};   // [mf(cc)][ib(i)] 64 AGPR
  float lr[4] = {};        // l partial per i-block

  // single-buffered fragments (named; reloaded right after last use)
  s16x8 qa00, qa01, qa10, qa11;   // [grp][ks]
  s16x8 vf0, vf1, vf2, vf3;       // [mf]

#define QLOAD(JT)                                                        \
  do {                                                                   \
    const ushort_t* qb = qp + (size_t)(JT) * 8192;                       \
    qa00 = *(const s16x8*)(qb);                                          \
    qa01 = *(const s16x8*)(qb + 32);                                     \
    qa10 = *(const s16x8*)(qb + 1024);                                   \
    qa11 = *(const s16x8*)(qb + 1056);                                   \
  } while (0)
#define VLOAD(JT)                                                        \
  do {                                                                   \
    const ushort_t* vbp = vp + (size_t)(JT) * 8192;                      \
    vf0 = *(const s16x8*)(vbp);                                          \
    vf1 = *(const s16x8*)(vbp + 2048);                                   \
    vf2 = *(const s16x8*)(vbp + 4096);                                   \
    vf3 = *(const s16x8*)(vbp + 6144);                                   \
  } while (0)

  QLOAD(0);
  VLOAD(0);
#pragma unroll 1
  for (int jt = 0; jt < 16; ++jt) {
    f32x4 st0[4], st1[4];
    __builtin_amdgcn_s_setprio(1);
#pragma unroll
    for (int ib = 0; ib < 4; ++ib) {
      f32x4 z = {};
      z = __builtin_amdgcn_mfma_f32_16x16x32_bf16(qa00, kf0[ib], z, 0, 0, 0);
      z = __builtin_amdgcn_mfma_f32_16x16x32_bf16(qa01, kf1[ib], z, 0, 0, 0);
      st0[ib] = z;
    }
#pragma unroll
    for (int ib = 0; ib < 4; ++ib) {
      f32x4 z = {};
      z = __builtin_amdgcn_mfma_f32_16x16x32_bf16(qa10, kf0[ib], z, 0, 0, 0);
      z = __builtin_amdgcn_mfma_f32_16x16x32_bf16(qa11, kf1[ib], z, 0, 0, 0);
      st1[ib] = z;
    }
    __builtin_amdgcn_s_setprio(0);
    QLOAD(jt + 1);   // qa dead after QK^T; ~exp+PV of cover before next use

    s16x8 pb[4];
#pragma unroll
    for (int ib = 0; ib < 4; ++ib) {
      const float e0 = fexp2(st0[ib][0]);
      const float e1 = fexp2(st0[ib][1]);
      const float e2 = fexp2(st0[ib][2]);
      const float e3 = fexp2(st0[ib][3]);
      const float e4 = fexp2(st1[ib][0]);
      const float e5 = fexp2(st1[ib][1]);
      const float e6 = fexp2(st1[ib][2]);
      const float e7 = fexp2(st1[ib][3]);
      lr[ib] += ((e0 + e1) + (e2 + e3)) + ((e4 + e5) + (e6 + e7));
      uint4 u;
      u.x = cvtpk(e0, e1);
      u.y = cvtpk(e2, e3);
      u.z = cvtpk(e4, e5);
      u.w = cvtpk(e6, e7);
      pb[ib] = __builtin_bit_cast(s16x8, u);
    }

    __builtin_amdgcn_s_setprio(1);
#pragma unroll
    for (int ib = 0; ib < 4; ++ib) {
      accO[0][ib] = __builtin_amdgcn_mfma_f32_16x16x32_bf16(
          vf0, pb[ib], accO[0][ib], 0, 0, 0);
      accO[1][ib] = __builtin_amdgcn_mfma_f32_16x16x32_bf16(
          vf1, pb[ib], accO[1][ib], 0, 0, 0);
      accO[2][ib] = __builtin_amdgcn_mfma_f32_16x16x32_bf16(
          vf2, pb[ib], accO[2][ib], 0, 0, 0);
      accO[3][ib] = __builtin_amdgcn_mfma_f32_16x16x32_bf16(
          vf3, pb[ib], accO[3][ib], 0, 0, 0);
    }
    __builtin_amdgcn_s_setprio(0);
    VLOAD(jt + 1);   // vf dead after PV
  }
#undef QLOAD
#undef VLOAD

  // ---- cross-wave reductions ----
  float* ldsL = (float*)(lds + 16384);
#pragma unroll
  for (int ib = 0; ib < 4; ++ib) {
    lr[ib] += __shfl_xor(lr[ib], 16);
    lr[ib] += __shfl_xor(lr[ib], 32);
  }
  if (lane < 16)
    *(float4*)(ldsL + (w * 16 + l15) * 4) =
        make_float4(lr[0], lr[1], lr[2], lr[3]);

  // accO tree-reduce: round r gathers i-block r into wave r
  float* red = (float*)lds;
  f32x4 rAcc[4];
#pragma unroll
  for (int r = 0; r < 4; ++r) {
#pragma unroll
    for (int mf = 0; mf < 4; ++mf)
      *(f32x4*)(red + w * 1024 + lane * 16 + ((mf ^ (lane & 3)) * 4)) =
          accO[mf][r];
    __syncthreads();
    if (w == r) {
#pragma unroll
      for (int mf = 0; mf < 4; ++mf) {
        f32x4 s = {};
#pragma unroll
        for (int w2 = 0; w2 < 4; ++w2)
          s += *(const f32x4*)(red + w2 * 1024 + lane * 16 +
                               ((mf ^ (lane & 3)) * 4));
        rAcc[mf] = s;
      }
    }
    __syncthreads();
  }

  // l sum across waves for this wave's i-block (ib == w)
  float lsum = 0.f;
#pragma unroll
  for (int w2 = 0; w2 < 4; ++w2) lsum += ldsL[(w2 * 16 + l15) * 4 + w];
  const float inv = 1.0f / lsum;

  // ---- epilogue: bf16 attn_t, swizzled k-major [b][i][c] ----
  unsigned* Pw = (unsigned*)(lds) + w * 512;  // reduce scratch, now free
  const int kk = 4 * (l15 & 7);
#pragma unroll
  for (int mf = 0; mf < 4; ++mf) {
    uint2 pk;
    pk.x = cvtpk(rAcc[mf][0] * inv, rAcc[mf][1] * inv);
    pk.y = cvtpk(rAcc[mf][2] * inv, rAcc[mf][3] * inv);
    const int dwb = 8 * mf + 2 * g;
    *(uint2*)&Pw[l15 * 32 + (dwb ^ kk)] = pk;
  }
  __syncthreads();
#pragma unroll
  for (int rep = 0; rep < 8; ++rep) {
    const int id = rep * 64 + lane;
    const int row = id >> 5, dw = id & 31;
    attn_t[((size_t)b * SEQ + i0 + 16 * w + row) * 256 + h * 32 + dw] =
        Pw[row * 32 + dw];
  }
}

// ---------------------------------------------------------------------------
extern "C" void kernel_launch(void* const* d_in, const int* in_sizes, int n_in,
                              void* d_out, int out_size, void* d_ws, size_t ws_size,
                              hipStream_t stream) {
  const float* x      = (const float*)d_in[0];
  const float* w_qkv  = (const float*)d_in[1];
  const float* b_qkv  = (const float*)d_in[2];
  const float* w_dw   = (const float*)d_in[3];
  const float* b_dw   = (const float*)d_in[4];
  const float* w_po   = (const float*)d_in[5];
  const float* b_po   = (const float*)d_in[6];
  const float* temp   = (const float*)d_in[7];
  float* out = (float*)d_out;
  float* ws  = (float*)d_ws;

  // workspace layout (float units)
  float* qkv_pre = ws;                            // 12,582,912 floats
  float* qkv     = ws + 12582912;                 // 12,582,912 floats (q,k used)
  float* rq      = ws + 25165824;                 // 2048
  float* rk      = ws + 25167872;                 // 524,288
  unsigned* xbt  = (unsigned*)(ws + 25692160);    // 2M dwords (8MB)
  unsigned* wqb  = (unsigned*)(ws + 27789312);    // 384K dwords
  unsigned* wpb  = (unsigned*)(ws + 28182528);    // 128K dwords
  // xbt region reused after QKV GEMM:
  unsigned* vb     = (unsigned*)(ws + 25692160);  // 2M dwords (dwconv2 output)
  // qkv_pre region reused after dwconv2:
  unsigned* qt     = (unsigned*)(ws);             // 2M dwords
  unsigned* kt     = (unsigned*)(ws + 2097152);   // 2M dwords
  unsigned* attn_t = (unsigned*)(ws + 4194304);   // 2M dwords

  // 0) bf16 conversions
  wprep<<<2048, 256, 0, stream>>>(w_qkv, w_po, wqb, wpb);
  xpose_bf16<<<dim3(SEQ / 64, DIM / 64, BATCH), 256, 0, stream>>>(x, xbt);

  // 1) QKV pointwise conv (bf16 MFMA)
  gemm_mfma_bf16<<<dim3(SEQ / 128, C3 / 128, BATCH), 256, 0, stream>>>(
      (const ushort_t*)wqb, (const ushort_t*)xbt, b_qkv, qkv_pre, C3, SEQ);

  // 2) depthwise conv; v -> bf16 vb directly, q/k -> f32 qkv; qnorm fused
  dwconv2<<<BATCH * C3, 256, 0, stream>>>(qkv_pre, w_dw, b_dw, qkv, vb, rq);

  // 3) k norm (q norm now fused into dwconv2)
  knorm_kernel<<<(BATCH * CH * SEQ) / 256, 256, 0, stream>>>(qkv, rk);

  // 4) bf16 prep of qt / kt (coalesced transpose; qt rows permuted)
  prep2<<<dim3(32, BATCH * HEADS, 2), 256, 0, stream>>>(
      qkv, rq, rk, temp, qt, kt);

  // 5) MFMA flash attention -> bf16 attn_t
  flash_mfma<<<dim3(SEQ / 64, BATCH * HEADS), 256, 0, stream>>>(
      (const ushort_t*)qt, (const ushort_t*)kt, (const ushort_t*)vb, attn_t);

  // 6) output pointwise conv (bf16 MFMA)
  gemm_mfma_bf16<<<dim3(SEQ / 128, DIM / 128, BATCH), 256, 0, stream>>>(
      (const ushort_t*)wpb, (const ushort_t*)attn_t, b_po, out, DIM, SEQ);
}

// Round 6
// 120.963 us; speedup vs baseline: 1.1934x; 1.1934x over previous
//
#include <hip/hip_runtime.h>
#include <hip/hip_bf16.h>

// Problem constants
#define BATCH 4
#define DIM 512
#define HEADS 8
#define CH 64          // DIM/HEADS
#define SEQ 2048
#define C3 1536        // 3*DIM
#define L2EPS 1e-12f

typedef float f32x4 __attribute__((ext_vector_type(4)));
typedef short s16x8 __attribute__((ext_vector_type(8)));
typedef unsigned short ushort_t;

// f32 pair -> packed bf16 pair (RNE) — bit version (memory-bound kernels)
static __device__ __forceinline__ unsigned bfpair(float a, float b) {
  unsigned ua = __builtin_bit_cast(unsigned, a);
  unsigned ub = __builtin_bit_cast(unsigned, b);
  ua = (ua + 0x7FFFu + ((ua >> 16) & 1u)) >> 16;
  ub = (ub + 0x7FFFu + ((ub >> 16) & 1u)) >> 16;
  return ua | (ub << 16);
}

// f32 pair -> packed bf16 pair via HW cvt (VALU-critical kernels)
static __device__ __forceinline__ unsigned cvtpk(float lo, float hi) {
  unsigned r;
  asm("v_cvt_pk_bf16_f32 %0, %1, %2" : "=v"(r) : "v"(lo), "v"(hi));
  return r;
}

// single-instruction exp2 (skip OCML's denormal-guard expansion; |x|<=~92 here)
static __device__ __forceinline__ float fexp2(float x) {
  float r;
  asm("v_exp_f32 %0, %1" : "=v"(r) : "v"(x));
  return r;
}

// async global->LDS, 16B per lane; lds dest must be wave-uniform base
static __device__ __forceinline__ void gl_lds16(const void* g, void* l) {
  __builtin_amdgcn_global_load_lds(
      (const __attribute__((address_space(1))) unsigned int*)g,
      (__attribute__((address_space(3))) unsigned int*)l, 16, 0, 0);
}

// ---------------------------------------------------------------------------
// Weight prep: f32 [M][512] -> bf16 [M][512], XOR-swizzled per 64-k chunk.
// ---------------------------------------------------------------------------
__global__ __launch_bounds__(256) void wprep(
    const float* __restrict__ wq, const float* __restrict__ wp,
    unsigned* __restrict__ wqb, unsigned* __restrict__ wpb) {
  const int id = blockIdx.x * 256 + threadIdx.x;
  const float* src;
  unsigned* dst;
  int rid;
  if (id < 1536 * 256) { src = wq; dst = wqb; rid = id; }
  else                 { src = wp; dst = wpb; rid = id - 1536 * 256; }
  const int m = rid >> 8, dcol = rid & 255;
  const int chunk = dcol >> 5, dw = dcol & 31;
  const int sdw = chunk * 32 + (dw ^ (4 * (m & 7)));
  const float* s = src + (size_t)m * 512 + 2 * sdw;
  dst[rid] = bfpair(s[0], s[1]);
}

// ---------------------------------------------------------------------------
// x transpose: f32 x[b][k][n] -> bf16 xbt[b][n][k], swizzled per 64-k chunk.
// ---------------------------------------------------------------------------
__global__ __launch_bounds__(256) void xpose_bf16(
    const float* __restrict__ x, unsigned* __restrict__ xbt) {
  __shared__ unsigned T[64][32];
  const int b = blockIdx.z;
  const int k0 = blockIdx.y * 64;
  const int n0 = blockIdx.x * 64;
  const int nl = threadIdx.x & 63;
  const int dwg = threadIdx.x >> 6;
  const float* xb = x + ((size_t)b * DIM + k0) * SEQ + n0 + nl;
#pragma unroll
  for (int dd = 0; dd < 8; ++dd) {
    const int dw = dwg * 8 + dd;
    const float v0 = xb[(size_t)(2 * dw) * SEQ];
    const float v1 = xb[(size_t)(2 * dw + 1) * SEQ];
    T[nl][dw ^ (4 * (nl & 7))] = bfpair(v0, v1);
  }
  __syncthreads();
#pragma unroll
  for (int rep = 0; rep < 8; ++rep) {
    const int id = rep * 256 + threadIdx.x;
    const int row = id >> 5, dw = id & 31;
    xbt[((size_t)b * SEQ + n0 + row) * 256 + (k0 >> 1) + dw] = T[row][dw];
  }
}

// ---------------------------------------------------------------------------
// bf16 MFMA GEMM: Y[b][m][n] = sum_k W[m][k] * B[b][n][k] + bias[m], K=512.
// ---------------------------------------------------------------------------
__global__ __launch_bounds__(256) void gemm_mfma_bf16(
    const ushort_t* __restrict__ Wb, const ushort_t* __restrict__ Bt,
    const float* __restrict__ bias, float* __restrict__ Y,
    int M, int N) {
  __shared__ __align__(16) char lds[32768];
  char* As = lds;
  char* Bs = lds + 16384;
  const int b = blockIdx.z;
  const int m0 = blockIdx.y * 128, n0 = blockIdx.x * 128;
  const int t = threadIdx.x, w = t >> 6, lane = t & 63;
  const int l15 = lane & 15, g = lane >> 4;
  const int key = 16 * (l15 & 7);
  const int wm = (w >> 1) * 64, wn = (w & 1) * 64;

  const int rsub = lane >> 3;
  const int csub = (lane & 7) * 8;

  f32x4 acc[4][4] = {};

  const ushort_t* Ag0 = Wb + (size_t)(m0 + 32 * w + rsub) * 512 + csub;
  const ushort_t* Bg0 = Bt + ((size_t)b * N + n0 + 32 * w + rsub) * 512 + csub;
  char* Al0 = As + (32 * w) * 128;
  char* Bl0 = Bs + (32 * w) * 128;

  for (int kc = 0; kc < 8; ++kc) {
    const int ko64 = kc * 64;
#pragma unroll
    for (int ri = 0; ri < 4; ++ri) {
      gl_lds16(Ag0 + (size_t)(8 * ri) * 512 + ko64, Al0 + ri * 1024);
      gl_lds16(Bg0 + (size_t)(8 * ri) * 512 + ko64, Bl0 + ri * 1024);
    }
    __syncthreads();
    const char* Abase = As + (wm + l15) * 128;
    const char* Bbase = Bs + (wn + l15) * 128;
#pragma unroll
    for (int ks = 0; ks < 2; ++ks) {
      const int ko = (64 * ks + 16 * g) ^ key;
      s16x8 af[4], bf[4];
#pragma unroll
      for (int mf = 0; mf < 4; ++mf) af[mf] = *(const s16x8*)(Abase + mf * 2048 + ko);
#pragma unroll
      for (int nf = 0; nf < 4; ++nf) bf[nf] = *(const s16x8*)(Bbase + nf * 2048 + ko);
#pragma unroll
      for (int mf = 0; mf < 4; ++mf)
#pragma unroll
        for (int nf = 0; nf < 4; ++nf)
          acc[mf][nf] = __builtin_amdgcn_mfma_f32_16x16x32_bf16(
              af[mf], bf[nf], acc[mf][nf], 0, 0, 0);
    }
    __syncthreads();
  }

#pragma unroll
  for (int mf = 0; mf < 4; ++mf) {
#pragma unroll
    for (int rg = 0; rg < 4; ++rg) {
      const int m = m0 + wm + 16 * mf + 4 * g + rg;
      const float bv = bias[m];
      float* yp = Y + ((size_t)b * M + m) * N + n0 + wn + l15;
#pragma unroll
      for (int nf = 0; nf < 4; ++nf)
        yp[16 * nf] = acc[mf][nf][rg] + bv;
    }
  }
}

// ---------------------------------------------------------------------------
// Depthwise conv k=3 pad=1 + bias. One block per (b,channel) row, 8 n/thread.
// q channels -> f32 qkv + fused qnorm; k -> f32 qkv
// v channels -> bf16 vb tile-major [bh][jt64][cc][32 dwords], dword
//               d ^ 4*(cc&7) swizzle (LDS-bank-spread for flash staging).
// ---------------------------------------------------------------------------
__global__ __launch_bounds__(256) void dwconv2(
    const float* __restrict__ pre, const float* __restrict__ wdw,
    const float* __restrict__ bdw, float* __restrict__ qkv,
    unsigned* __restrict__ vb, float* __restrict__ rq) {
  __shared__ float red[4];
  const int row = blockIdx.x;           // b*1536 + o
  const int o = row % C3;
  const int b = row / C3;
  const int n0 = threadIdx.x * 8;
  const float* src = pre + (size_t)row * SEQ + n0;
  float4 m0 = *(const float4*)src;
  float4 m1 = *(const float4*)(src + 4);
  const float left  = (n0 > 0) ? src[-1] : 0.f;
  const float right = (n0 < SEQ - 8) ? src[8] : 0.f;
  const float w0 = wdw[o * 3 + 0], w1 = wdw[o * 3 + 1], w2 = wdw[o * 3 + 2];
  const float bv = bdw[o];
  const float mid[8] = {m0.x, m0.y, m0.z, m0.w, m1.x, m1.y, m1.z, m1.w};
  const float lf[8]  = {left, m0.x, m0.y, m0.z, m0.w, m1.x, m1.y, m1.z};
  const float rt[8]  = {m0.y, m0.z, m0.w, m1.x, m1.y, m1.z, m1.w, right};
  float y[8];
#pragma unroll
  for (int u = 0; u < 8; ++u) y[u] = w0 * lf[u] + w1 * mid[u] + w2 * rt[u] + bv;

  if (o < 2 * DIM) {
    float* dst = qkv + (size_t)row * SEQ + n0;
    *(float4*)dst = make_float4(y[0], y[1], y[2], y[3]);
    *(float4*)(dst + 4) = make_float4(y[4], y[5], y[6], y[7]);
    if (o < DIM) {  // uniform branch: whole block is one q row
      float s = 0.f;
#pragma unroll
      for (int u = 0; u < 8; ++u) s += y[u] * y[u];
#pragma unroll
      for (int off = 32; off > 0; off >>= 1) s += __shfl_down(s, off);
      if ((threadIdx.x & 63) == 0) red[threadIdx.x >> 6] = s;
      __syncthreads();
      if (threadIdx.x == 0) {
        const float tv = red[0] + red[1] + red[2] + red[3];
        rq[b * DIM + o] = 1.0f / fmaxf(sqrtf(tv), L2EPS);
      }
    }
  } else {
    const int oc = o - 2 * DIM;
    const int h = oc >> 6, cc = oc & 63;
    const int bh = b * 8 + h;
    const int jt = n0 >> 6, d0 = (n0 & 63) >> 1;
    uint4 pk;
    pk.x = bfpair(y[0], y[1]); pk.y = bfpair(y[2], y[3]);
    pk.z = bfpair(y[4], y[5]); pk.w = bfpair(y[6], y[7]);
    *(uint4*)&vb[((size_t)(bh * 32 + jt) * 64 + cc) * 32 +
                 (d0 ^ (4 * (cc & 7)))] = pk;
  }
}

// ---------------------------------------------------------------------------
// k norm over HEAD axis: rk[b][cc][n]
// ---------------------------------------------------------------------------
__global__ __launch_bounds__(256) void knorm_kernel(
    const float* __restrict__ qkv, float* __restrict__ rk) {
  const int idx = blockIdx.x * 256 + threadIdx.x;
  const int n = idx & (SEQ - 1);
  const int cc = (idx >> 11) & 63;
  const int b = idx >> 17;
  const float* base = qkv + ((size_t)b * C3 + DIM + cc) * SEQ + n;
  float s = 0.f;
#pragma unroll
  for (int h = 0; h < HEADS; ++h) {
    float v = base[(size_t)h * CH * SEQ];
    s += v * v;
  }
  rk[idx] = 1.0f / fmaxf(sqrtf(s), L2EPS);
}

// ---------------------------------------------------------------------------
// prep2: coalesced LDS-transpose build of qt / kt.
//  sec0 (qt): rows PERMUTED per 32-row slice — actual row jl goes to slice
//    position 16*((jl>>2)&1) + 4*(jl>>3) + (jl&3). This makes the QK^T
//    C-layout (row m=4g+rg at chunk jf) hold actual j = 32*(jf>>1) + 8g +
//    4*(jf&1) + rg, i.e. exp(st) packed with e=4*(jf&1)+rg is a valid K=32
//    PV B-operand with k == natural j. Rows re-swizzled by DEST row
//    (dw ^ 4*(dr&7)) for bank-spread LDS reads in flash.  *rq applied.
//  sec1 (kt): plain layout, * rk * temp * log2(e).
// ---------------------------------------------------------------------------
__global__ __launch_bounds__(256) void prep2(
    const float* __restrict__ qkv, const float* __restrict__ rq,
    const float* __restrict__ rk, const float* __restrict__ temp,
    unsigned* __restrict__ qt, unsigned* __restrict__ kt) {
  __shared__ unsigned T[64][32];
  const int jt = blockIdx.x, bh = blockIdx.y, sec = blockIdx.z;
  const int b = bh >> 3, h = bh & 7;
  const int jl = threadIdx.x & 63, dwg = threadIdx.x >> 6;
  const int j = jt * 64 + jl;
  if (sec == 0) {
    const float* base = qkv + ((size_t)b * C3 + h * CH) * SEQ + j;
    const float* rqb = rq + b * DIM + h * CH;
#pragma unroll
    for (int dd = 0; dd < 8; ++dd) {
      const int dw = dwg * 8 + dd;
      float v0 = base[(size_t)(2 * dw) * SEQ] * rqb[2 * dw];
      float v1 = base[(size_t)(2 * dw + 1) * SEQ] * rqb[2 * dw + 1];
      T[jl][dw ^ (4 * (jl & 7))] = bfpair(v0, v1);
    }
  } else {
    const float f = temp[h] * 1.44269504f;
    const float* base = qkv + ((size_t)b * C3 + DIM + h * CH) * SEQ + j;
    const float* rkb = rk + (size_t)b * CH * SEQ + j;
#pragma unroll
    for (int dd = 0; dd < 8; ++dd) {
      const int dw = dwg * 8 + dd;
      float v0 = base[(size_t)(2 * dw) * SEQ] * rkb[(size_t)(2 * dw) * SEQ] * f;
      float v1 = base[(size_t)(2 * dw + 1) * SEQ] * rkb[(size_t)(2 * dw + 1) * SEQ] * f;
      T[jl][dw ^ (4 * (jl & 7))] = bfpair(v0, v1);
    }
  }
  __syncthreads();
  unsigned* dst = (sec == 0 ? qt : kt) + ((size_t)bh * SEQ + jt * 64) * 32;
#pragma unroll
  for (int rep = 0; rep < 8; ++rep) {
    const int id = rep * 256 + threadIdx.x;
    const int row = id >> 5, dw = id & 31;
    const unsigned val = T[row][dw ^ (4 * (row & 7))];
    if (sec == 0) {
      const int s = row >> 5, rl = row & 31;
      const int dr = (s << 5) | (16 * ((rl >> 2) & 1) + 4 * (rl >> 3) + (rl & 3));
      dst[dr * 32 + (dw ^ (4 * (dr & 7)))] = val;
    } else {
      dst[row * 32 + dw] = val;
    }
  }
}

// ---------------------------------------------------------------------------
// Flash attention v7 = R1's proven 2-phase dbuf LDS skeleton + in-register P.
//  Wave w owns i-strip [i0+16w, +16) (K frags resident), iterates all 64-j
//  tiles; Q and V staged in LDS (shared by 4 waves) via gl_lds, double-
//  buffered, 1 barrier/tile. The permuted qt makes QK^T's C feed PV's K=32
//  B-operand directly: P = exp2(st) -> cvt_pk -> pb regs. No P LDS round
//  trip (was 4 ds_write + 2 ds_read + lgkm stall), LDS 40->32KB, regs ~90
//  -> launch_bounds(256,4): full 1024-block grid resident in one round.
// ---------------------------------------------------------------------------
__global__ __launch_bounds__(256, 4) void flash_mfma(
    const ushort_t* __restrict__ qt, const ushort_t* __restrict__ kt,
    const ushort_t* __restrict__ vb, unsigned* __restrict__ attn_t) {
  __shared__ __align__(16) char lds[32768];
  char* const Q0 = lds;             // [64 pos][128B]
  char* const Q1 = lds + 8192;
  char* const V0 = lds + 16384;     // [64 cc][128B]
  char* const V1 = lds + 24576;

  // XCD-aware bijective swizzle: each XCD handles 4 bh values (L2 locality)
  const int orig = blockIdx.y * 32 + blockIdx.x;
  const int swz = (orig & 7) * 128 + (orig >> 3);
  const int bh = swz >> 5, b = bh >> 3, h = bh & 7;
  const int i0 = (swz & 31) * 64;

  const int t = threadIdx.x, w = t >> 6, lane = t & 63;
  const int l15 = lane & 15, g = lane >> 4;
  const int key = 16 * (lane & 7);

  const ushort_t* ktp =
      kt + ((size_t)bh * SEQ + i0 + 16 * w + l15) * 64 + 8 * g;
  const s16x8 kfrag0 = *(const s16x8*)(ktp);
  const s16x8 kfrag1 = *(const s16x8*)(ktp + 32);

  const ushort_t* qtile = qt + (size_t)bh * SEQ * 64;    // + jt*4096
  const ushort_t* vtile = vb + (size_t)bh * 32 * 4096;   // + jt*4096

  // wave-level staging: 2 chunks of 1KB each for Q and V
  const int li0 = (w * 2) * 64 + lane;
  const int li1 = li0 + 64;
  const int wo = (w * 2) * 1024;

  f32x4 accO[4] = {};
  float l_run = 0.f;

#define FSTAGE(JT, QD, VD)                                               \
  do {                                                                   \
    gl_lds16(qtile + (size_t)(JT) * 4096 + li0 * 8, (QD) + wo);          \
    gl_lds16(qtile + (size_t)(JT) * 4096 + li1 * 8, (QD) + wo + 1024);   \
    gl_lds16(vtile + (size_t)(JT) * 4096 + li0 * 8, (VD) + wo);          \
    gl_lds16(vtile + (size_t)(JT) * 4096 + li1 * 8, (VD) + wo + 1024);   \
  } while (0)

  auto compute = [&](const char* Qs, const char* Vs) {
    f32x4 st[4];
    __builtin_amdgcn_s_setprio(1);
#pragma unroll
    for (int jf = 0; jf < 4; ++jf) {
      const char* qrow = Qs + (16 * jf + l15) * 128;
      s16x8 a0 = *(const s16x8*)(qrow + ((16 * g) ^ key));
      s16x8 a1 = *(const s16x8*)(qrow + ((16 * g + 64) ^ key));
      f32x4 z = {};
      z = __builtin_amdgcn_mfma_f32_16x16x32_bf16(a0, kfrag0, z, 0, 0, 0);
      z = __builtin_amdgcn_mfma_f32_16x16x32_bf16(a1, kfrag1, z, 0, 0, 0);
      st[jf] = z;
    }
    __builtin_amdgcn_s_setprio(0);

    // P = exp2(st) in regs; permuted qt makes pb a valid K=32 B-operand
    // (element e = 4*(jf&1)+rg, k = 8g+e == natural j within the 32-chunk)
    s16x8 pb[2];
#pragma unroll
    for (int ks = 0; ks < 2; ++ks) {
      const float e0 = fexp2(st[2 * ks][0]);
      const float e1 = fexp2(st[2 * ks][1]);
      const float e2 = fexp2(st[2 * ks][2]);
      const float e3 = fexp2(st[2 * ks][3]);
      const float e4 = fexp2(st[2 * ks + 1][0]);
      const float e5 = fexp2(st[2 * ks + 1][1]);
      const float e6 = fexp2(st[2 * ks + 1][2]);
      const float e7 = fexp2(st[2 * ks + 1][3]);
      l_run += ((e0 + e1) + (e2 + e3)) + ((e4 + e5) + (e6 + e7));
      uint4 u;
      u.x = cvtpk(e0, e1);
      u.y = cvtpk(e2, e3);
      u.z = cvtpk(e4, e5);
      u.w = cvtpk(e6, e7);
      pb[ks] = __builtin_bit_cast(s16x8, u);
    }

    __builtin_amdgcn_s_setprio(1);
#pragma unroll
    for (int ks = 0; ks < 2; ++ks)
#pragma unroll
      for (int mf = 0; mf < 4; ++mf) {
        const char* vrow = Vs + (16 * mf + l15) * 128;
        s16x8 aV = *(const s16x8*)(vrow + ((16 * g + 64 * ks) ^ key));
        accO[mf] = __builtin_amdgcn_mfma_f32_16x16x32_bf16(
            aV, pb[ks], accO[mf], 0, 0, 0);
      }
    __builtin_amdgcn_s_setprio(0);
  };

  FSTAGE(0, Q0, V0);
  __syncthreads();
#pragma unroll 1
  for (int jt2 = 0; jt2 < 16; ++jt2) {
    const int jt = 2 * jt2;
    FSTAGE(jt + 1, Q1, V1);          // overlaps with compute below
    compute(Q0, V0);
    __syncthreads();                 // vmcnt(0) drain: Q1/V1 now ready
    if (jt2 < 15) FSTAGE(jt + 2, Q0, V0);
    compute(Q1, V1);
    __syncthreads();
  }

  // ---- deferred l reduction over the 4 j-row-groups ----
  l_run += __shfl_xor(l_run, 16);
  l_run += __shfl_xor(l_run, 32);
  const float inv = 1.0f / l_run;

  // ---- epilogue: bf16 attn_t, swizzled k-major [b][i][c] ----
  unsigned* Pw = (unsigned*)(lds + w * 2048);  // Q0 region, now free
  const int kk = 4 * (l15 & 7);
#pragma unroll
  for (int mf = 0; mf < 4; ++mf) {
    uint2 pk;
    pk.x = cvtpk(accO[mf][0] * inv, accO[mf][1] * inv);
    pk.y = cvtpk(accO[mf][2] * inv, accO[mf][3] * inv);
    const int dwb = 8 * mf + 2 * g;
    *(uint2*)&Pw[l15 * 32 + (dwb ^ kk)] = pk;
  }
  __syncthreads();
#pragma unroll
  for (int rep = 0; rep < 8; ++rep) {
    const int id = rep * 64 + lane;
    const int row = id >> 5, dw = id & 31;
    attn_t[((size_t)b * SEQ + i0 + 16 * w + row) * 256 + h * 32 + dw] =
        Pw[row * 32 + dw];
  }
#undef FSTAGE
}

// ---------------------------------------------------------------------------
extern "C" void kernel_launch(void* const* d_in, const int* in_sizes, int n_in,
                              void* d_out, int out_size, void* d_ws, size_t ws_size,
                              hipStream_t stream) {
  const float* x      = (const float*)d_in[0];
  const float* w_qkv  = (const float*)d_in[1];
  const float* b_qkv  = (const float*)d_in[2];
  const float* w_dw   = (const float*)d_in[3];
  const float* b_dw   = (const float*)d_in[4];
  const float* w_po   = (const float*)d_in[5];
  const float* b_po   = (const float*)d_in[6];
  const float* temp   = (const float*)d_in[7];
  float* out = (float*)d_out;
  float* ws  = (float*)d_ws;

  // workspace layout (float units)
  float* qkv_pre = ws;                            // 12,582,912 floats
  float* qkv     = ws + 12582912;                 // 12,582,912 floats (q,k used)
  float* rq      = ws + 25165824;                 // 2048
  float* rk      = ws + 25167872;                 // 524,288
  unsigned* xbt  = (unsigned*)(ws + 25692160);    // 2M dwords (8MB)
  unsigned* wqb  = (unsigned*)(ws + 27789312);    // 384K dwords
  unsigned* wpb  = (unsigned*)(ws + 28182528);    // 128K dwords
  // xbt region reused after QKV GEMM:
  unsigned* vb     = (unsigned*)(ws + 25692160);  // 2M dwords (dwconv2 output)
  // qkv_pre region reused after dwconv2:
  unsigned* qt     = (unsigned*)(ws);             // 2M dwords
  unsigned* kt     = (unsigned*)(ws + 2097152);   // 2M dwords
  unsigned* attn_t = (unsigned*)(ws + 4194304);   // 2M dwords

  // 0) bf16 conversions
  wprep<<<2048, 256, 0, stream>>>(w_qkv, w_po, wqb, wpb);
  xpose_bf16<<<dim3(SEQ / 64, DIM / 64, BATCH), 256, 0, stream>>>(x, xbt);

  // 1) QKV pointwise conv (bf16 MFMA)
  gemm_mfma_bf16<<<dim3(SEQ / 128, C3 / 128, BATCH), 256, 0, stream>>>(
      (const ushort_t*)wqb, (const ushort_t*)xbt, b_qkv, qkv_pre, C3, SEQ);

  // 2) depthwise conv; v -> bf16 vb directly, q/k -> f32 qkv; qnorm fused
  dwconv2<<<BATCH * C3, 256, 0, stream>>>(qkv_pre, w_dw, b_dw, qkv, vb, rq);

  // 3) k norm (q norm fused into dwconv2)
  knorm_kernel<<<(BATCH * CH * SEQ) / 256, 256, 0, stream>>>(qkv, rk);

  // 4) bf16 prep of qt / kt (coalesced transpose; qt rows permuted+swizzled)
  prep2<<<dim3(32, BATCH * HEADS, 2), 256, 0, stream>>>(
      qkv, rq, rk, temp, qt, kt);

  // 5) MFMA flash attention -> bf16 attn_t
  flash_mfma<<<dim3(SEQ / 64, BATCH * HEADS), 256, 0, stream>>>(
      (const ushort_t*)qt, (const ushort_t*)kt, (const ushort_t*)vb, attn_t);

  // 6) output pointwise conv (bf16 MFMA)
  gemm_mfma_bf16<<<dim3(SEQ / 128, DIM / 128, BATCH), 256, 0, stream>>>(
      (const ushort_t*)wpb, (const ushort_t*)attn_t, b_po, out, DIM, SEQ);
}

// Round 7
// 117.174 us; speedup vs baseline: 1.2320x; 1.0323x over previous
//
#include <hip/hip_runtime.h>
#include <hip/hip_bf16.h>

// Problem constants
#define BATCH 4
#define DIM 512
#define HEADS 8
#define CH 64          // DIM/HEADS
#define SEQ 2048
#define C3 1536        // 3*DIM
#define L2EPS 1e-12f

typedef float f32x4 __attribute__((ext_vector_type(4)));
typedef short s16x8 __attribute__((ext_vector_type(8)));
typedef unsigned short ushort_t;

// f32 pair -> packed bf16 pair (RNE) — bit version (memory-bound kernels)
static __device__ __forceinline__ unsigned bfpair(float a, float b) {
  unsigned ua = __builtin_bit_cast(unsigned, a);
  unsigned ub = __builtin_bit_cast(unsigned, b);
  ua = (ua + 0x7FFFu + ((ua >> 16) & 1u)) >> 16;
  ub = (ub + 0x7FFFu + ((ub >> 16) & 1u)) >> 16;
  return ua | (ub << 16);
}

// f32 pair -> packed bf16 pair via HW cvt (VALU-critical kernels)
static __device__ __forceinline__ unsigned cvtpk(float lo, float hi) {
  unsigned r;
  asm("v_cvt_pk_bf16_f32 %0, %1, %2" : "=v"(r) : "v"(lo), "v"(hi));
  return r;
}

// single-instruction exp2 (skip OCML's denormal-guard expansion; |x|<=~92 here)
static __device__ __forceinline__ float fexp2(float x) {
  float r;
  asm("v_exp_f32 %0, %1" : "=v"(r) : "v"(x));
  return r;
}

// async global->LDS, 16B per lane; lds dest must be wave-uniform base
static __device__ __forceinline__ void gl_lds16(const void* g, void* l) {
  __builtin_amdgcn_global_load_lds(
      (const __attribute__((address_space(1))) unsigned int*)g,
      (__attribute__((address_space(3))) unsigned int*)l, 16, 0, 0);
}

// ---------------------------------------------------------------------------
// Weight prep: f32 [M][512] -> bf16 [M][512], XOR-swizzled per 64-k chunk.
// ---------------------------------------------------------------------------
__global__ __launch_bounds__(256) void wprep(
    const float* __restrict__ wq, const float* __restrict__ wp,
    unsigned* __restrict__ wqb, unsigned* __restrict__ wpb) {
  const int id = blockIdx.x * 256 + threadIdx.x;
  const float* src;
  unsigned* dst;
  int rid;
  if (id < 1536 * 256) { src = wq; dst = wqb; rid = id; }
  else                 { src = wp; dst = wpb; rid = id - 1536 * 256; }
  const int m = rid >> 8, dcol = rid & 255;
  const int chunk = dcol >> 5, dw = dcol & 31;
  const int sdw = chunk * 32 + (dw ^ (4 * (m & 7)));
  const float* s = src + (size_t)m * 512 + 2 * sdw;
  dst[rid] = bfpair(s[0], s[1]);
}

// ---------------------------------------------------------------------------
// x transpose: f32 x[b][k][n] -> bf16 xbt[b][n][k], swizzled per 64-k chunk.
// ---------------------------------------------------------------------------
__global__ __launch_bounds__(256) void xpose_bf16(
    const float* __restrict__ x, unsigned* __restrict__ xbt) {
  __shared__ unsigned T[64][32];
  const int b = blockIdx.z;
  const int k0 = blockIdx.y * 64;
  const int n0 = blockIdx.x * 64;
  const int nl = threadIdx.x & 63;
  const int dwg = threadIdx.x >> 6;
  const float* xb = x + ((size_t)b * DIM + k0) * SEQ + n0 + nl;
#pragma unroll
  for (int dd = 0; dd < 8; ++dd) {
    const int dw = dwg * 8 + dd;
    const float v0 = xb[(size_t)(2 * dw) * SEQ];
    const float v1 = xb[(size_t)(2 * dw + 1) * SEQ];
    T[nl][dw ^ (4 * (nl & 7))] = bfpair(v0, v1);
  }
  __syncthreads();
#pragma unroll
  for (int rep = 0; rep < 8; ++rep) {
    const int id = rep * 256 + threadIdx.x;
    const int row = id >> 5, dw = id & 31;
    xbt[((size_t)b * SEQ + n0 + row) * 256 + (k0 >> 1) + dw] = T[row][dw];
  }
}

// ---------------------------------------------------------------------------
// bf16 MFMA GEMM: Y[b][m][n] = sum_k W[m][k] * B[b][n][k] + bias[m], K=512.
// ---------------------------------------------------------------------------
__global__ __launch_bounds__(256) void gemm_mfma_bf16(
    const ushort_t* __restrict__ Wb, const ushort_t* __restrict__ Bt,
    const float* __restrict__ bias, float* __restrict__ Y,
    int M, int N) {
  __shared__ __align__(16) char lds[32768];
  char* As = lds;
  char* Bs = lds + 16384;
  const int b = blockIdx.z;
  const int m0 = blockIdx.y * 128, n0 = blockIdx.x * 128;
  const int t = threadIdx.x, w = t >> 6, lane = t & 63;
  const int l15 = lane & 15, g = lane >> 4;
  const int key = 16 * (l15 & 7);
  const int wm = (w >> 1) * 64, wn = (w & 1) * 64;

  const int rsub = lane >> 3;
  const int csub = (lane & 7) * 8;

  f32x4 acc[4][4] = {};

  const ushort_t* Ag0 = Wb + (size_t)(m0 + 32 * w + rsub) * 512 + csub;
  const ushort_t* Bg0 = Bt + ((size_t)b * N + n0 + 32 * w + rsub) * 512 + csub;
  char* Al0 = As + (32 * w) * 128;
  char* Bl0 = Bs + (32 * w) * 128;

  for (int kc = 0; kc < 8; ++kc) {
    const int ko64 = kc * 64;
#pragma unroll
    for (int ri = 0; ri < 4; ++ri) {
      gl_lds16(Ag0 + (size_t)(8 * ri) * 512 + ko64, Al0 + ri * 1024);
      gl_lds16(Bg0 + (size_t)(8 * ri) * 512 + ko64, Bl0 + ri * 1024);
    }
    __syncthreads();
    const char* Abase = As + (wm + l15) * 128;
    const char* Bbase = Bs + (wn + l15) * 128;
#pragma unroll
    for (int ks = 0; ks < 2; ++ks) {
      const int ko = (64 * ks + 16 * g) ^ key;
      s16x8 af[4], bf[4];
#pragma unroll
      for (int mf = 0; mf < 4; ++mf) af[mf] = *(const s16x8*)(Abase + mf * 2048 + ko);
#pragma unroll
      for (int nf = 0; nf < 4; ++nf) bf[nf] = *(const s16x8*)(Bbase + nf * 2048 + ko);
#pragma unroll
      for (int mf = 0; mf < 4; ++mf)
#pragma unroll
        for (int nf = 0; nf < 4; ++nf)
          acc[mf][nf] = __builtin_amdgcn_mfma_f32_16x16x32_bf16(
              af[mf], bf[nf], acc[mf][nf], 0, 0, 0);
    }
    __syncthreads();
  }

#pragma unroll
  for (int mf = 0; mf < 4; ++mf) {
#pragma unroll
    for (int rg = 0; rg < 4; ++rg) {
      const int m = m0 + wm + 16 * mf + 4 * g + rg;
      const float bv = bias[m];
      float* yp = Y + ((size_t)b * M + m) * N + n0 + wn + l15;
#pragma unroll
      for (int nf = 0; nf < 4; ++nf)
        yp[16 * nf] = acc[mf][nf][rg] + bv;
    }
  }
}

// ---------------------------------------------------------------------------
// Depthwise conv k=3 pad=1 + bias. One block per (b,channel) row, 8 n/thread.
// q channels -> f32 qkv + fused qnorm; k -> f32 qkv
// v channels -> bf16 vb tile-major [bh][jt64][cc][32 dwords], dword
//               d ^ 4*(cc&7) swizzle (LDS-bank-spread for flash staging).
// ---------------------------------------------------------------------------
__global__ __launch_bounds__(256) void dwconv2(
    const float* __restrict__ pre, const float* __restrict__ wdw,
    const float* __restrict__ bdw, float* __restrict__ qkv,
    unsigned* __restrict__ vb, float* __restrict__ rq) {
  __shared__ float red[4];
  const int row = blockIdx.x;           // b*1536 + o
  const int o = row % C3;
  const int b = row / C3;
  const int n0 = threadIdx.x * 8;
  const float* src = pre + (size_t)row * SEQ + n0;
  float4 m0 = *(const float4*)src;
  float4 m1 = *(const float4*)(src + 4);
  const float left  = (n0 > 0) ? src[-1] : 0.f;
  const float right = (n0 < SEQ - 8) ? src[8] : 0.f;
  const float w0 = wdw[o * 3 + 0], w1 = wdw[o * 3 + 1], w2 = wdw[o * 3 + 2];
  const float bv = bdw[o];
  const float mid[8] = {m0.x, m0.y, m0.z, m0.w, m1.x, m1.y, m1.z, m1.w};
  const float lf[8]  = {left, m0.x, m0.y, m0.z, m0.w, m1.x, m1.y, m1.z};
  const float rt[8]  = {m0.y, m0.z, m0.w, m1.x, m1.y, m1.z, m1.w, right};
  float y[8];
#pragma unroll
  for (int u = 0; u < 8; ++u) y[u] = w0 * lf[u] + w1 * mid[u] + w2 * rt[u] + bv;

  if (o < 2 * DIM) {
    float* dst = qkv + (size_t)row * SEQ + n0;
    *(float4*)dst = make_float4(y[0], y[1], y[2], y[3]);
    *(float4*)(dst + 4) = make_float4(y[4], y[5], y[6], y[7]);
    if (o < DIM) {  // uniform branch: whole block is one q row
      float s = 0.f;
#pragma unroll
      for (int u = 0; u < 8; ++u) s += y[u] * y[u];
#pragma unroll
      for (int off = 32; off > 0; off >>= 1) s += __shfl_down(s, off);
      if ((threadIdx.x & 63) == 0) red[threadIdx.x >> 6] = s;
      __syncthreads();
      if (threadIdx.x == 0) {
        const float tv = red[0] + red[1] + red[2] + red[3];
        rq[b * DIM + o] = 1.0f / fmaxf(sqrtf(tv), L2EPS);
      }
    }
  } else {
    const int oc = o - 2 * DIM;
    const int h = oc >> 6, cc = oc & 63;
    const int bh = b * 8 + h;
    const int jt = n0 >> 6, d0 = (n0 & 63) >> 1;
    uint4 pk;
    pk.x = bfpair(y[0], y[1]); pk.y = bfpair(y[2], y[3]);
    pk.z = bfpair(y[4], y[5]); pk.w = bfpair(y[6], y[7]);
    *(uint4*)&vb[((size_t)(bh * 32 + jt) * 64 + cc) * 32 +
                 (d0 ^ (4 * (cc & 7)))] = pk;
  }
}

// ---------------------------------------------------------------------------
// k norm over HEAD axis: rk[b][cc][n]
// ---------------------------------------------------------------------------
__global__ __launch_bounds__(256) void knorm_kernel(
    const float* __restrict__ qkv, float* __restrict__ rk) {
  const int idx = blockIdx.x * 256 + threadIdx.x;
  const int n = idx & (SEQ - 1);
  const int cc = (idx >> 11) & 63;
  const int b = idx >> 17;
  const float* base = qkv + ((size_t)b * C3 + DIM + cc) * SEQ + n;
  float s = 0.f;
#pragma unroll
  for (int h = 0; h < HEADS; ++h) {
    float v = base[(size_t)h * CH * SEQ];
    s += v * v;
  }
  rk[idx] = 1.0f / fmaxf(sqrtf(s), L2EPS);
}

// ---------------------------------------------------------------------------
// prep2: coalesced LDS-transpose build of qt / kt.
//  sec0 (qt): rows PERMUTED per 32-row slice — actual row jl goes to slice
//    position 16*((jl>>2)&1) + 4*(jl>>3) + (jl&3). This makes the QK^T
//    C-layout (row m=4g+rg at chunk jf) hold actual j = 32*(jf>>1) + 8g +
//    4*(jf&1) + rg, i.e. exp(st) packed with e=4*(jf&1)+rg is a valid K=32
//    PV B-operand with k == natural j. Rows re-swizzled by DEST row
//    (dw ^ 4*(dr&7)) for bank-spread LDS reads in flash.  *rq applied.
//  sec1 (kt): plain layout, * rk * temp * log2(e).
// ---------------------------------------------------------------------------
__global__ __launch_bounds__(256) void prep2(
    const float* __restrict__ qkv, const float* __restrict__ rq,
    const float* __restrict__ rk, const float* __restrict__ temp,
    unsigned* __restrict__ qt, unsigned* __restrict__ kt) {
  __shared__ unsigned T[64][32];
  const int jt = blockIdx.x, bh = blockIdx.y, sec = blockIdx.z;
  const int b = bh >> 3, h = bh & 7;
  const int jl = threadIdx.x & 63, dwg = threadIdx.x >> 6;
  const int j = jt * 64 + jl;
  if (sec == 0) {
    const float* base = qkv + ((size_t)b * C3 + h * CH) * SEQ + j;
    const float* rqb = rq + b * DIM + h * CH;
#pragma unroll
    for (int dd = 0; dd < 8; ++dd) {
      const int dw = dwg * 8 + dd;
      float v0 = base[(size_t)(2 * dw) * SEQ] * rqb[2 * dw];
      float v1 = base[(size_t)(2 * dw + 1) * SEQ] * rqb[2 * dw + 1];
      T[jl][dw ^ (4 * (jl & 7))] = bfpair(v0, v1);
    }
  } else {
    const float f = temp[h] * 1.44269504f;
    const float* base = qkv + ((size_t)b * C3 + DIM + h * CH) * SEQ + j;
    const float* rkb = rk + (size_t)b * CH * SEQ + j;
#pragma unroll
    for (int dd = 0; dd < 8; ++dd) {
      const int dw = dwg * 8 + dd;
      float v0 = base[(size_t)(2 * dw) * SEQ] * rkb[(size_t)(2 * dw) * SEQ] * f;
      float v1 = base[(size_t)(2 * dw + 1) * SEQ] * rkb[(size_t)(2 * dw + 1) * SEQ] * f;
      T[jl][dw ^ (4 * (jl & 7))] = bfpair(v0, v1);
    }
  }
  __syncthreads();
  unsigned* dst = (sec == 0 ? qt : kt) + ((size_t)bh * SEQ + jt * 64) * 32;
#pragma unroll
  for (int rep = 0; rep < 8; ++rep) {
    const int id = rep * 256 + threadIdx.x;
    const int row = id >> 5, dw = id & 31;
    const unsigned val = T[row][dw ^ (4 * (row & 7))];
    if (sec == 0) {
      const int s = row >> 5, rl = row & 31;
      const int dr = (s << 5) | (16 * ((rl >> 2) & 1) + 4 * (rl >> 3) + (rl & 3));
      dst[dr * 32 + (dw ^ (4 * (dr & 7)))] = val;
    } else {
      dst[row * 32 + dw] = val;
    }
  }
}

// ---------------------------------------------------------------------------
// Flash attention v8 = v7 skeleton + 32-i wave strips (block covers 128 i).
//  LDS-read amplification halved: Q/V operand reads (8+8 ds_read_b128 per
//  wave-tile) are SHARED across the wave's two 16-i blocks — only K-frags,
//  st/pb, and accO duplicate. Per-CU LDS cycles ~49k vs ~98k in v7 (was 88%
//  of wall). Grid 512 blocks (16 i-tiles x 32 bh); half the barriers; half
//  the Q/V refetch. P stays in registers (qt row-permutation).
// ---------------------------------------------------------------------------
__global__ __launch_bounds__(256, 2) void flash_mfma(
    const ushort_t* __restrict__ qt, const ushort_t* __restrict__ kt,
    const ushort_t* __restrict__ vb, unsigned* __restrict__ attn_t) {
  __shared__ __align__(16) char lds[32768];
  char* const Q0 = lds;             // [64 pos][128B]
  char* const Q1 = lds + 8192;
  char* const V0 = lds + 16384;     // [64 cc][128B]
  char* const V1 = lds + 24576;

  // XCD-aware bijective swizzle over 512 blocks: 64 per XCD = 4 bh values
  // (qt+kt+vb per bh = 768KB; 4 bh ~ 3MB fits the 4MB XCD L2)
  const int orig = blockIdx.y * 16 + blockIdx.x;
  const int swz = (orig & 7) * 64 + (orig >> 3);
  const int bh = swz >> 4, b = bh >> 3, h = bh & 7;
  const int i0 = (swz & 15) * 128;

  const int t = threadIdx.x, w = t >> 6, lane = t & 63;
  const int l15 = lane & 15, g = lane >> 4;
  const int key = 16 * (lane & 7);

  // K fragments for the wave's two 16-i blocks: 32 VGPR
  const ushort_t* ktp =
      kt + ((size_t)bh * SEQ + i0 + 32 * w + l15) * 64 + 8 * g;
  s16x8 kf0[2], kf1[2];
#pragma unroll
  for (int ib = 0; ib < 2; ++ib) {
    kf0[ib] = *(const s16x8*)(ktp + ib * 1024);
    kf1[ib] = *(const s16x8*)(ktp + ib * 1024 + 32);
  }

  const ushort_t* qtile = qt + (size_t)bh * SEQ * 64;    // + jt*4096
  const ushort_t* vtile = vb + (size_t)bh * 32 * 4096;   // + jt*4096

  // wave-level staging: 2 chunks of 1KB each for Q and V
  const int li0 = (w * 2) * 64 + lane;
  const int li1 = li0 + 64;
  const int wo = (w * 2) * 1024;

  f32x4 accO[4][2] = {};   // [mf(cc)][ib]
  float lr[2] = {};

#define FSTAGE(JT, QD, VD)                                               \
  do {                                                                   \
    gl_lds16(qtile + (size_t)(JT) * 4096 + li0 * 8, (QD) + wo);          \
    gl_lds16(qtile + (size_t)(JT) * 4096 + li1 * 8, (QD) + wo + 1024);   \
    gl_lds16(vtile + (size_t)(JT) * 4096 + li0 * 8, (VD) + wo);          \
    gl_lds16(vtile + (size_t)(JT) * 4096 + li1 * 8, (VD) + wo + 1024);   \
  } while (0)

  auto compute = [&](const char* Qs, const char* Vs) {
    f32x4 st[4][2];
    __builtin_amdgcn_s_setprio(1);
#pragma unroll
    for (int jf = 0; jf < 4; ++jf) {
      const char* qrow = Qs + (16 * jf + l15) * 128;
      s16x8 a0 = *(const s16x8*)(qrow + ((16 * g) ^ key));
      s16x8 a1 = *(const s16x8*)(qrow + ((16 * g + 64) ^ key));
#pragma unroll
      for (int ib = 0; ib < 2; ++ib) {
        f32x4 z = {};
        z = __builtin_amdgcn_mfma_f32_16x16x32_bf16(a0, kf0[ib], z, 0, 0, 0);
        z = __builtin_amdgcn_mfma_f32_16x16x32_bf16(a1, kf1[ib], z, 0, 0, 0);
        st[jf][ib] = z;
      }
    }
    __builtin_amdgcn_s_setprio(0);

    // P = exp2(st) in regs; permuted qt makes pb a valid K=32 B-operand
    s16x8 pb[2][2];
#pragma unroll
    for (int ib = 0; ib < 2; ++ib)
#pragma unroll
      for (int ks = 0; ks < 2; ++ks) {
        const float e0 = fexp2(st[2 * ks][ib][0]);
        const float e1 = fexp2(st[2 * ks][ib][1]);
        const float e2 = fexp2(st[2 * ks][ib][2]);
        const float e3 = fexp2(st[2 * ks][ib][3]);
        const float e4 = fexp2(st[2 * ks + 1][ib][0]);
        const float e5 = fexp2(st[2 * ks + 1][ib][1]);
        const float e6 = fexp2(st[2 * ks + 1][ib][2]);
        const float e7 = fexp2(st[2 * ks + 1][ib][3]);
        lr[ib] += ((e0 + e1) + (e2 + e3)) + ((e4 + e5) + (e6 + e7));
        uint4 u;
        u.x = cvtpk(e0, e1);
        u.y = cvtpk(e2, e3);
        u.z = cvtpk(e4, e5);
        u.w = cvtpk(e6, e7);
        pb[ib][ks] = __builtin_bit_cast(s16x8, u);
      }

    __builtin_amdgcn_s_setprio(1);
#pragma unroll
    for (int ks = 0; ks < 2; ++ks)
#pragma unroll
      for (int mf = 0; mf < 4; ++mf) {
        const char* vrow = Vs + (16 * mf + l15) * 128;
        s16x8 aV = *(const s16x8*)(vrow + ((16 * g + 64 * ks) ^ key));
#pragma unroll
        for (int ib = 0; ib < 2; ++ib)
          accO[mf][ib] = __builtin_amdgcn_mfma_f32_16x16x32_bf16(
              aV, pb[ib][ks], accO[mf][ib], 0, 0, 0);
      }
    __builtin_amdgcn_s_setprio(0);
  };

  FSTAGE(0, Q0, V0);
  __syncthreads();
#pragma unroll 1
  for (int jt2 = 0; jt2 < 16; ++jt2) {
    const int jt = 2 * jt2;
    FSTAGE(jt + 1, Q1, V1);          // overlaps with compute below
    compute(Q0, V0);
    __syncthreads();                 // vmcnt(0) drain: Q1/V1 now ready
    if (jt2 < 15) FSTAGE(jt + 2, Q0, V0);
    compute(Q1, V1);
    __syncthreads();
  }

  // ---- deferred l reduction over the 4 j-row-groups ----
  float inv[2];
#pragma unroll
  for (int ib = 0; ib < 2; ++ib) {
    lr[ib] += __shfl_xor(lr[ib], 16);
    lr[ib] += __shfl_xor(lr[ib], 32);
    inv[ib] = 1.0f / lr[ib];
  }

  // ---- epilogue: bf16 attn_t, swizzled k-major [b][i][c] ----
  unsigned* Pw = (unsigned*)(lds + w * 4096);  // 32 rows x 128B per wave
  const int kk = 4 * (l15 & 7);
#pragma unroll
  for (int ib = 0; ib < 2; ++ib)
#pragma unroll
    for (int mf = 0; mf < 4; ++mf) {
      uint2 pk;
      pk.x = cvtpk(accO[mf][ib][0] * inv[ib], accO[mf][ib][1] * inv[ib]);
      pk.y = cvtpk(accO[mf][ib][2] * inv[ib], accO[mf][ib][3] * inv[ib]);
      const int dwb = 8 * mf + 2 * g;
      *(uint2*)&Pw[(16 * ib + l15) * 32 + (dwb ^ kk)] = pk;
    }
  __syncthreads();
#pragma unroll
  for (int rep = 0; rep < 16; ++rep) {
    const int id = rep * 64 + lane;
    const int row = id >> 5, dw = id & 31;
    attn_t[((size_t)b * SEQ + i0 + 32 * w + row) * 256 + h * 32 + dw] =
        Pw[row * 32 + dw];
  }
#undef FSTAGE
}

// ---------------------------------------------------------------------------
extern "C" void kernel_launch(void* const* d_in, const int* in_sizes, int n_in,
                              void* d_out, int out_size, void* d_ws, size_t ws_size,
                              hipStream_t stream) {
  const float* x      = (const float*)d_in[0];
  const float* w_qkv  = (const float*)d_in[1];
  const float* b_qkv  = (const float*)d_in[2];
  const float* w_dw   = (const float*)d_in[3];
  const float* b_dw   = (const float*)d_in[4];
  const float* w_po   = (const float*)d_in[5];
  const float* b_po   = (const float*)d_in[6];
  const float* temp   = (const float*)d_in[7];
  float* out = (float*)d_out;
  float* ws  = (float*)d_ws;

  // workspace layout (float units)
  float* qkv_pre = ws;                            // 12,582,912 floats
  float* qkv     = ws + 12582912;                 // 12,582,912 floats (q,k used)
  float* rq      = ws + 25165824;                 // 2048
  float* rk      = ws + 25167872;                 // 524,288
  unsigned* xbt  = (unsigned*)(ws + 25692160);    // 2M dwords (8MB)
  unsigned* wqb  = (unsigned*)(ws + 27789312);    // 384K dwords
  unsigned* wpb  = (unsigned*)(ws + 28182528);    // 128K dwords
  // xbt region reused after QKV GEMM:
  unsigned* vb     = (unsigned*)(ws + 25692160);  // 2M dwords (dwconv2 output)
  // qkv_pre region reused after dwconv2:
  unsigned* qt     = (unsigned*)(ws);             // 2M dwords
  unsigned* kt     = (unsigned*)(ws + 2097152);   // 2M dwords
  unsigned* attn_t = (unsigned*)(ws + 4194304);   // 2M dwords

  // 0) bf16 conversions
  wprep<<<2048, 256, 0, stream>>>(w_qkv, w_po, wqb, wpb);
  xpose_bf16<<<dim3(SEQ / 64, DIM / 64, BATCH), 256, 0, stream>>>(x, xbt);

  // 1) QKV pointwise conv (bf16 MFMA)
  gemm_mfma_bf16<<<dim3(SEQ / 128, C3 / 128, BATCH), 256, 0, stream>>>(
      (const ushort_t*)wqb, (const ushort_t*)xbt, b_qkv, qkv_pre, C3, SEQ);

  // 2) depthwise conv; v -> bf16 vb directly, q/k -> f32 qkv; qnorm fused
  dwconv2<<<BATCH * C3, 256, 0, stream>>>(qkv_pre, w_dw, b_dw, qkv, vb, rq);

  // 3) k norm (q norm fused into dwconv2)
  knorm_kernel<<<(BATCH * CH * SEQ) / 256, 256, 0, stream>>>(qkv, rk);

  // 4) bf16 prep of qt / kt (coalesced transpose; qt rows permuted+swizzled)
  prep2<<<dim3(32, BATCH * HEADS, 2), 256, 0, stream>>>(
      qkv, rq, rk, temp, qt, kt);

  // 5) MFMA flash attention -> bf16 attn_t (128-i blocks, 32-i wave strips)
  flash_mfma<<<dim3(SEQ / 128, BATCH * HEADS), 256, 0, stream>>>(
      (const ushort_t*)qt, (const ushort_t*)kt, (const ushort_t*)vb, attn_t);

  // 6) output pointwise conv (bf16 MFMA)
  gemm_mfma_bf16<<<dim3(SEQ / 128, DIM / 128, BATCH), 256, 0, stream>>>(
      (const ushort_t*)wpb, (const ushort_t*)attn_t, b_po, out, DIM, SEQ);
}